// Round 14
// baseline (117.239 us; speedup 1.0000x reference)
//
#include <hip/hip_runtime.h>
#include <math.h>

#define Bq 128
#define Nn 8
#define LQ 32
#define LD 256
#define DD 128
#define EPSN 1e-12f
#define NEGV (-9999.0f)

typedef __attribute__((ext_vector_type(8))) short short8v;
typedef __attribute__((ext_vector_type(4))) int   int4v;
typedef __attribute__((ext_vector_type(4))) float f32x4;

__device__ __forceinline__ unsigned bf16_rne_hibits(float x) {
    unsigned u = __float_as_uint(x);
    return (u + 0x7FFFu + ((u >> 16) & 1u)) & 0xFFFF0000u;
}

// ---------------- Kernel 1: normalize q rows, emit SWIZZLED bf16 planes ----
// (round 12, verified): 16B chunk c -> c ^ (row&7) within each 256B row;
// maxsim stages linearly to LDS and reads with the same XOR -> conflict-free.
__global__ __launch_bounds__(256) void qnorm_k(const float* __restrict__ q,
                                               unsigned short* __restrict__ qh,
                                               unsigned short* __restrict__ ql) {
    int row  = blockIdx.x * 4 + (threadIdx.x >> 6);   // 4096 rows = [B][LQ]
    int lane = threadIdx.x & 63;
    size_t base = (size_t)row * DD + lane * 2;
    float2 v = *reinterpret_cast<const float2*>(q + base);
    float ss = v.x * v.x + v.y * v.y;
#pragma unroll
    for (int o = 32; o; o >>= 1) ss += __shfl_xor(ss, o);
    float inv = 1.0f / fmaxf(sqrtf(ss), EPSN);
    float x0 = v.x * inv, x1 = v.y * inv;
    unsigned h0 = bf16_rne_hibits(x0), h1 = bf16_rne_hibits(x1);
    float l0 = x0 - __uint_as_float(h0);
    float l1 = x1 - __uint_as_float(h1);
    unsigned g0 = bf16_rne_hibits(l0), g1 = bf16_rne_hibits(l1);
    unsigned swz = ((unsigned)(lane * 2)) ^ (((unsigned)row & 7u) << 3);
    *reinterpret_cast<unsigned*>(qh + (size_t)row * DD + swz) = (h0 >> 16) | h1;
    *reinterpret_cast<unsigned*>(ql + (size_t)row * DD + swz) = (g0 >> 16) | g1;
}

// ---------------- Kernel 2: MaxSim via MFMA, dual-stream, DEPTH-4 ----------
// Round-12 structure (63.5us: one (n,b) block, both tensors, LDS q, trunc
// cvt) + round-14 change: d prefetch depth 2 -> 4 rotating buffer sets
// (P/Q/R/S per stream). Consuming ks_i of tile nt issues the load of ks_i
// of tile nt+1 -> uniform 4-KSTEP prefetch distance, steady-state 8 chunks
// (128B/lane) outstanding. Rationale: issue-work is ~6us total; measured
// 1.4-2.3 TB/s matches Little's law at the old 64B/lane in-flight, so the
// limiter is outstanding-bytes, NOT occupancy (64-reg band proven
// infeasible in r8/9/13). +32 staging regs: ~116 < 128 band cap, pinned by
// __launch_bounds__(256,4). Spill signature: VGPR==128 + WRITE >60MB.
__global__ __launch_bounds__(256, 4) void maxsim_k(const float* __restrict__ d_cq,
                                                   const float* __restrict__ d_orig,
                                                   const int* __restrict__ mask,
                                                   const unsigned short* __restrict__ qh,
                                                   const unsigned short* __restrict__ ql,
                                                   float* __restrict__ scores) {
    __shared__ float4 qstage[1024];   // 16KB: [0,512)=qh plane, [512,1024)=ql
    __shared__ float wma[4][32];
    __shared__ float wmb[4][32];

    int nb = blockIdx.x;              // n*Bq + b, [0,1024)
    int b  = nb & 127;
    int n  = nb >> 7;

    int tid  = threadIdx.x;
    int w    = tid >> 6;              // wave id: d-rows [w*64, w*64+64)
    int lane = tid & 63;
    int r    = lane & 15;             // B-frag col / C col (local d-row)
    int g    = lane >> 4;             // k-group (8 elems each)

    {   // stage swizzled q planes -> LDS (linear copy preserves swizzle)
        const float4* srch = reinterpret_cast<const float4*>(qh + (size_t)b * LQ * DD);
        const float4* srcl = reinterpret_cast<const float4*>(ql + (size_t)b * LQ * DD);
        qstage[tid]       = srch[tid];
        qstage[tid + 256] = srch[tid + 256];
        qstage[tid + 512] = srcl[tid];
        qstage[tid + 768] = srcl[tid + 256];
    }
    __syncthreads();

    const unsigned short* qh_lds = reinterpret_cast<const unsigned short*>(qstage);
    const unsigned short* ql_lds = qh_lds + LQ * DD;
    unsigned swz8 = ((unsigned)r & 7u) << 3;   // read-side XOR (elem units)

    f32x4 rm0a = {NEGV, NEGV, NEGV, NEGV}, rm1a = {NEGV, NEGV, NEGV, NEGV};
    f32x4 rm0b = {NEGV, NEGV, NEGV, NEGV}, rm1b = {NEGV, NEGV, NEGV, NEGV};

#define SB __builtin_amdgcn_sched_barrier(0)

// truncation hi/lo split (round-8/12 verified: absmax 0.0)
#define CVT2(DH, DL, W, X0, X1, SSQ)                                           \
    { unsigned u0 = __float_as_uint(X0), u1 = __float_as_uint(X1);             \
      DH[W] = (int)((u0 >> 16) | (u1 & 0xFFFF0000u));                          \
      float l0 = (X0) - __uint_as_float(u0 & 0xFFFF0000u);                     \
      float l1 = (X1) - __uint_as_float(u1 & 0xFFFF0000u);                     \
      DL[W] = (int)((__float_as_uint(l0) >> 16) |                              \
                    (__float_as_uint(l1) & 0xFFFF0000u));                      \
      SSQ += (X0)*(X0) + (X1)*(X1); }

// One k-slice, both streams. Consume (CA0,CA1)/(CB0,CB1); refill them with
// the PFOFF prefetch (WAR-safe by program order: cvt reads precede the
// reassignment); A-frags from swizzled LDS; 12 MFMAs.
#define KSTEP(CA0, CA1, CB0, CB1, KS, PFOFF)                                   \
    {                                                                          \
        unsigned aoff = (((unsigned)(KS) * 32u) + (unsigned)g * 8u) ^ swz8;    \
        short8v a0h = *reinterpret_cast<const short8v*>(qh_lds + r * DD + aoff);          \
        short8v a0l = *reinterpret_cast<const short8v*>(ql_lds + r * DD + aoff);          \
        short8v a1h = *reinterpret_cast<const short8v*>(qh_lds + (r + 16) * DD + aoff);   \
        short8v a1l = *reinterpret_cast<const short8v*>(ql_lds + (r + 16) * DD + aoff);   \
        int4v dhwa, dlwa, dhwb, dlwb;                                          \
        CVT2(dhwa, dlwa, 0, CA0.x, CA0.y, ssqa)                                \
        CVT2(dhwa, dlwa, 1, CA0.z, CA0.w, ssqa)                                \
        CVT2(dhwa, dlwa, 2, CA1.x, CA1.y, ssqa)                                \
        CVT2(dhwa, dlwa, 3, CA1.z, CA1.w, ssqa)                                \
        CA0 = *reinterpret_cast<const float4*>(prow_a + (PFOFF));              \
        CA1 = *reinterpret_cast<const float4*>(prow_a + (PFOFF) + 4);          \
        CVT2(dhwb, dlwb, 0, CB0.x, CB0.y, ssqb)                                \
        CVT2(dhwb, dlwb, 1, CB0.z, CB0.w, ssqb)                                \
        CVT2(dhwb, dlwb, 2, CB1.x, CB1.y, ssqb)                                \
        CVT2(dhwb, dlwb, 3, CB1.z, CB1.w, ssqb)                                \
        CB0 = *reinterpret_cast<const float4*>(prow_b + (PFOFF));              \
        CB1 = *reinterpret_cast<const float4*>(prow_b + (PFOFF) + 4);          \
        short8v dha = __builtin_bit_cast(short8v, dhwa);                       \
        short8v dla = __builtin_bit_cast(short8v, dlwa);                       \
        c0a = __builtin_amdgcn_mfma_f32_16x16x32_bf16(a0h, dha, c0a, 0, 0, 0); \
        c1a = __builtin_amdgcn_mfma_f32_16x16x32_bf16(a1h, dha, c1a, 0, 0, 0); \
        c0a = __builtin_amdgcn_mfma_f32_16x16x32_bf16(a0h, dla, c0a, 0, 0, 0); \
        c1a = __builtin_amdgcn_mfma_f32_16x16x32_bf16(a1h, dla, c1a, 0, 0, 0); \
        c0a = __builtin_amdgcn_mfma_f32_16x16x32_bf16(a0l, dha, c0a, 0, 0, 0); \
        c1a = __builtin_amdgcn_mfma_f32_16x16x32_bf16(a1l, dha, c1a, 0, 0, 0); \
        short8v dhb = __builtin_bit_cast(short8v, dhwb);                       \
        short8v dlb = __builtin_bit_cast(short8v, dlwb);                       \
        c0b = __builtin_amdgcn_mfma_f32_16x16x32_bf16(a0h, dhb, c0b, 0, 0, 0); \
        c1b = __builtin_amdgcn_mfma_f32_16x16x32_bf16(a1h, dhb, c1b, 0, 0, 0); \
        c0b = __builtin_amdgcn_mfma_f32_16x16x32_bf16(a0h, dlb, c0b, 0, 0, 0); \
        c1b = __builtin_amdgcn_mfma_f32_16x16x32_bf16(a1h, dlb, c1b, 0, 0, 0); \
        c0b = __builtin_amdgcn_mfma_f32_16x16x32_bf16(a0l, dhb, c0b, 0, 0, 0); \
        c1b = __builtin_amdgcn_mfma_f32_16x16x32_bf16(a1l, dhb, c1b, 0, 0, 0); \
    }

    // per-lane row pointers for the two streams (same geometry, two tensors)
    const float* prow_a = d_cq   + (size_t)nb * (LD * DD) + (size_t)(w * 64 + r) * DD + g * 8;
    const float* prow_b = d_orig + (size_t)nb * (LD * DD) + (size_t)(w * 64 + r) * DD + g * 8;

    // prologue: fill all 4 chunk sets (ks0..ks3) for both streams -> 16
    // dwordx4 issued back-to-back, deep MLP from the first cycle
    float4 Pa0 = *reinterpret_cast<const float4*>(prow_a);
    float4 Pa1 = *reinterpret_cast<const float4*>(prow_a + 4);
    float4 Pb0 = *reinterpret_cast<const float4*>(prow_b);
    float4 Pb1 = *reinterpret_cast<const float4*>(prow_b + 4);
    float4 Qa0 = *reinterpret_cast<const float4*>(prow_a + 32);
    float4 Qa1 = *reinterpret_cast<const float4*>(prow_a + 36);
    float4 Qb0 = *reinterpret_cast<const float4*>(prow_b + 32);
    float4 Qb1 = *reinterpret_cast<const float4*>(prow_b + 36);
    float4 Ra0 = *reinterpret_cast<const float4*>(prow_a + 64);
    float4 Ra1 = *reinterpret_cast<const float4*>(prow_a + 68);
    float4 Rb0 = *reinterpret_cast<const float4*>(prow_b + 64);
    float4 Rb1 = *reinterpret_cast<const float4*>(prow_b + 68);
    float4 Sa0 = *reinterpret_cast<const float4*>(prow_a + 96);
    float4 Sa1 = *reinterpret_cast<const float4*>(prow_a + 100);
    float4 Sb0 = *reinterpret_cast<const float4*>(prow_b + 96);
    float4 Sb1 = *reinterpret_cast<const float4*>(prow_b + 100);

#pragma unroll 1
    for (int nt = 0; nt < 4; ++nt) {
        int drow = w * 64 + nt * 16 + r;

        f32x4 c0a = {0.f, 0.f, 0.f, 0.f}, c1a = {0.f, 0.f, 0.f, 0.f};
        f32x4 c0b = {0.f, 0.f, 0.f, 0.f}, c1b = {0.f, 0.f, 0.f, 0.f};
        float ssqa = 0.0f, ssqb = 0.0f;

        int mk = mask[(size_t)nb * LD + drow];    // shared by both tensors
        int nnoff = (nt < 3) ? 2048 : 0;          // next-nt (16 rows) or clamp

        KSTEP(Pa0, Pa1, Pb0, Pb1, 0, nnoff);      SB;   // fetch nt+1 ks0 -> P
        KSTEP(Qa0, Qa1, Qb0, Qb1, 1, nnoff + 32); SB;   // fetch nt+1 ks1 -> Q
        KSTEP(Ra0, Ra1, Rb0, Rb1, 2, nnoff + 64); SB;   // fetch nt+1 ks2 -> R
        KSTEP(Sa0, Sa1, Sb0, Sb1, 3, nnoff + 96); SB;   // fetch nt+1 ks3 -> S

        ssqa += __shfl_xor(ssqa, 16);  ssqa += __shfl_xor(ssqa, 32);
        ssqb += __shfl_xor(ssqb, 16);  ssqb += __shfl_xor(ssqb, 32);
        float inva = 1.0f / fmaxf(sqrtf(ssqa), EPSN);
        float invb = 1.0f / fmaxf(sqrtf(ssqb), EPSN);

        // C layout: col = lane&15 = local d-row; row(lq) = g*4+i (+16 for c1)
#pragma unroll
        for (int i = 0; i < 4; ++i) {
            rm0a[i] = fmaxf(rm0a[i], mk ? c0a[i] * inva : NEGV);
            rm1a[i] = fmaxf(rm1a[i], mk ? c1a[i] * inva : NEGV);
            rm0b[i] = fmaxf(rm0b[i], mk ? c0b[i] * invb : NEGV);
            rm1b[i] = fmaxf(rm1b[i], mk ? c1b[i] * invb : NEGV);
        }
        prow_a += 16 * DD;
        prow_b += 16 * DD;
    }
#undef KSTEP
#undef CVT2

    // max over the wave's 64 d-rows: reduce across the 16 cols (lane&15)
#pragma unroll
    for (int i = 0; i < 4; ++i) {
#pragma unroll
        for (int o = 1; o <= 8; o <<= 1) {
            rm0a[i] = fmaxf(rm0a[i], __shfl_xor(rm0a[i], o));
            rm1a[i] = fmaxf(rm1a[i], __shfl_xor(rm1a[i], o));
            rm0b[i] = fmaxf(rm0b[i], __shfl_xor(rm0b[i], o));
            rm1b[i] = fmaxf(rm1b[i], __shfl_xor(rm1b[i], o));
        }
    }
    if (r == 0) {
#pragma unroll
        for (int i = 0; i < 4; ++i) {
            wma[w][g * 4 + i]      = rm0a[i];
            wma[w][16 + g * 4 + i] = rm1a[i];
            wmb[w][g * 4 + i]      = rm0b[i];
            wmb[w][16 + g * 4 + i] = rm1b[i];
        }
    }
    __syncthreads();

    if (tid < 64) {   // lanes 0-31: cq, lanes 32-63: orig; l = lq
        int tau = tid >> 5, l = tid & 31;
        const float (*wm)[32] = tau ? wmb : wma;
        float v = fmaxf(fmaxf(wm[0][l], wm[1][l]),
                        fmaxf(wm[2][l], wm[3][l]));
#pragma unroll
        for (int o = 1; o <= 16; o <<= 1) v += __shfl_xor(v, o);
        if (l == 0)
            scores[tau * (Bq * Nn) + b * Nn + n] = v;
    }
}

// ---------------- Kernel 3: log_softmax + KL ----------------
__global__ void loss_k(const float* __restrict__ scores, float* __restrict__ out) {
    int tid = threadIdx.x;   // 128 threads, one per b
    const float* s = scores + tid * Nn;            // student (cq)
    const float* t = scores + Bq * Nn + tid * Nn;  // teacher (orig)
    float sv[Nn], tv[Nn];
#pragma unroll
    for (int n = 0; n < Nn; ++n) { sv[n] = s[n]; tv[n] = t[n]; }
    float ms = sv[0], mt = tv[0];
#pragma unroll
    for (int n = 1; n < Nn; ++n) { ms = fmaxf(ms, sv[n]); mt = fmaxf(mt, tv[n]); }
    float es = 0.0f, et = 0.0f;
#pragma unroll
    for (int n = 0; n < Nn; ++n) { es += expf(sv[n] - ms); et += expf(tv[n] - mt); }
    float lses = ms + logf(es);
    float lset = mt + logf(et);
    double kl = 0.0;
#pragma unroll
    for (int n = 0; n < Nn; ++n) {
        float lt = tv[n] - lset;
        float ls = sv[n] - lses;
        kl += (double)expf(lt) * ((double)lt - (double)ls);
    }
#pragma unroll
    for (int o = 32; o; o >>= 1) kl += __shfl_xor(kl, o);
    __shared__ double part[2];
    if ((tid & 63) == 0) part[tid >> 6] = kl;
    __syncthreads();
    if (tid == 0) out[0] = (float)((part[0] + part[1]) / (double)Bq);
}

extern "C" void kernel_launch(void* const* d_in, const int* in_sizes, int n_in,
                              void* d_out, int out_size, void* d_ws, size_t ws_size,
                              hipStream_t stream) {
    const float* q     = (const float*)d_in[0];
    const float* dcq   = (const float*)d_in[1];
    const float* dorig = (const float*)d_in[2];
    const int*   mask  = (const int*)d_in[3];
    // labels (d_in[4]) unused by the reference loss path

    unsigned short* qh = (unsigned short*)d_ws;                  // [B][32][128] bf16-hi (swizzled rows), 1MB
    unsigned short* ql = qh + (size_t)Bq * LQ * DD;              // bf16-lo (swizzled rows), 1MB
    float* scores      = (float*)(ql + (size_t)Bq * LQ * DD);    // [2][B][N], 8KB

    qnorm_k<<<(Bq * LQ) / 4, 256, 0, stream>>>(q, qh, ql);
    maxsim_k<<<Nn * Bq, 256, 0, stream>>>(dcq, dorig, mask, qh, ql, scores);
    loss_k<<<1, 128, 0, stream>>>(scores, (float*)d_out);
}

// Round 16
// 64.154 us; speedup vs baseline: 1.8275x; 1.8275x over previous
//
#include <hip/hip_runtime.h>
#include <math.h>

#define Bq 128
#define Nn 8
#define LQ 32
#define LD 256
#define DD 128
#define EPSN 1e-12f
#define NEGV (-9999.0f)

typedef __attribute__((ext_vector_type(8))) short short8v;
typedef __attribute__((ext_vector_type(4))) int   int4v;
typedef __attribute__((ext_vector_type(4))) float f32x4;

__device__ __forceinline__ unsigned bf16_rne_hibits(float x) {
    unsigned u = __float_as_uint(x);
    return (u + 0x7FFFu + ((u >> 16) & 1u)) & 0xFFFF0000u;
}

// ---------------- Kernel 1: normalize q rows, emit SWIZZLED bf16 planes ----
// (round 12, verified): 16B chunk c -> c ^ (row&7) within each 256B row;
// maxsim stages linearly to LDS and reads with the same XOR -> conflict-free.
__global__ __launch_bounds__(256) void qnorm_k(const float* __restrict__ q,
                                               unsigned short* __restrict__ qh,
                                               unsigned short* __restrict__ ql) {
    int row  = blockIdx.x * 4 + (threadIdx.x >> 6);   // 4096 rows = [B][LQ]
    int lane = threadIdx.x & 63;
    size_t base = (size_t)row * DD + lane * 2;
    float2 v = *reinterpret_cast<const float2*>(q + base);
    float ss = v.x * v.x + v.y * v.y;
#pragma unroll
    for (int o = 32; o; o >>= 1) ss += __shfl_xor(ss, o);
    float inv = 1.0f / fmaxf(sqrtf(ss), EPSN);
    float x0 = v.x * inv, x1 = v.y * inv;
    unsigned h0 = bf16_rne_hibits(x0), h1 = bf16_rne_hibits(x1);
    float l0 = x0 - __uint_as_float(h0);
    float l1 = x1 - __uint_as_float(h1);
    unsigned g0 = bf16_rne_hibits(l0), g1 = bf16_rne_hibits(l1);
    unsigned swz = ((unsigned)(lane * 2)) ^ (((unsigned)row & 7u) << 3);
    *reinterpret_cast<unsigned*>(qh + (size_t)row * DD + swz) = (h0 >> 16) | h1;
    *reinterpret_cast<unsigned*>(ql + (size_t)row * DD + swz) = (g0 >> 16) | g1;
}

// ---------------- Kernel 2: MaxSim via MFMA, dual-stream, asm-counted vmcnt
// Round-12 schedule EXACTLY (63.5us verified: distance-2 refills 64/96/
// nnoff/nnoff+32 over TWO buffer sets) -- round 15's failure was wrong
// refill offsets (claimed depth-4 with 2 buffers; step2 consumed nt+1 ks0
// as ks2), NOT the vmcnt mechanism. Round-16:
//  - d loads inline-asm global_load_dwordx4 (invisible to compiler waitcnt)
//  - counted `s_waitcnt vmcnt(4)` + SB at each KSTEP top: waits exactly the
//    4 chunks consumed, keeps 4 newer in flight; no compiler full-drains
//  - vmcnt(0)+SB at prologue->loop and at every nt back-edge: no asm load
//    is in flight across a control-flow join (kills phi-copy hazard)
//  - all compiler-tracked vmem (q stage, masks) drained before first GLOAD
__global__ __launch_bounds__(256) void maxsim_k(const float* __restrict__ d_cq,
                                                const float* __restrict__ d_orig,
                                                const int* __restrict__ mask,
                                                const unsigned short* __restrict__ qh,
                                                const unsigned short* __restrict__ ql,
                                                float* __restrict__ scores) {
    __shared__ float4 qstage[1024];   // 16KB: [0,512)=qh plane, [512,1024)=ql
    __shared__ float wma[4][32];
    __shared__ float wmb[4][32];

    int nb = blockIdx.x;              // n*Bq + b, [0,1024)
    int b  = nb & 127;
    int n  = nb >> 7;

    int tid  = threadIdx.x;
    int w    = tid >> 6;              // wave id: d-rows [w*64, w*64+64)
    int lane = tid & 63;
    int r    = lane & 15;             // B-frag col / C col (local d-row)
    int g    = lane >> 4;             // k-group (8 elems each)

    {   // stage swizzled q planes -> LDS (linear copy preserves swizzle)
        const float4* srch = reinterpret_cast<const float4*>(qh + (size_t)b * LQ * DD);
        const float4* srcl = reinterpret_cast<const float4*>(ql + (size_t)b * LQ * DD);
        qstage[tid]       = srch[tid];
        qstage[tid + 256] = srch[tid + 256];
        qstage[tid + 512] = srcl[tid];
        qstage[tid + 768] = srcl[tid + 256];
    }
    __syncthreads();

    const unsigned short* qh_lds = reinterpret_cast<const unsigned short*>(qstage);
    const unsigned short* ql_lds = qh_lds + LQ * DD;
    unsigned swz8 = ((unsigned)r & 7u) << 3;   // read-side XOR (elem units)

    // preload masks (compiler-tracked), force to regs, drain vmcnt to 0 so
    // no compiler vmem wait with a wrong count survives into the loop.
    const int* mrow = mask + (size_t)nb * LD + w * 64 + r;
    int mk0 = mrow[0], mk1 = mrow[16], mk2 = mrow[32], mk3 = mrow[48];
    asm volatile("" :: "v"(mk0), "v"(mk1), "v"(mk2), "v"(mk3));
    asm volatile("s_waitcnt vmcnt(0)");
    __builtin_amdgcn_sched_barrier(0);

    f32x4 rm0a = {NEGV, NEGV, NEGV, NEGV}, rm1a = {NEGV, NEGV, NEGV, NEGV};
    f32x4 rm0b = {NEGV, NEGV, NEGV, NEGV}, rm1b = {NEGV, NEGV, NEGV, NEGV};

#define SB __builtin_amdgcn_sched_barrier(0)
#define GLOAD(DST, PTR) \
    asm volatile("global_load_dwordx4 %0, %1, off" : "=v"(DST) : "v"(PTR))
#define WAITV4 { asm volatile("s_waitcnt vmcnt(4)"); SB; }
#define DRAIN0 { asm volatile("s_waitcnt vmcnt(0)"); SB; }

// truncation hi/lo split (round-8/12 verified: absmax 0.0)
#define CVT2(DH, DL, W, X0, X1, SSQ)                                           \
    { unsigned u0 = __float_as_uint(X0), u1 = __float_as_uint(X1);             \
      DH[W] = (int)((u0 >> 16) | (u1 & 0xFFFF0000u));                          \
      float l0 = (X0) - __uint_as_float(u0 & 0xFFFF0000u);                     \
      float l1 = (X1) - __uint_as_float(u1 & 0xFFFF0000u);                     \
      DL[W] = (int)((__float_as_uint(l0) >> 16) |                              \
                    (__float_as_uint(l1) & 0xFFFF0000u));                      \
      SSQ += (X0)*(X0) + (X1)*(X1); }

// One k-slice, both streams. WAITV4 lands exactly the 4 chunks consumed
// (issued 2 KSTEPs ago); refill GLOADs below restore 8 in flight.
#define KSTEP(CA0, CA1, CB0, CB1, KS, PFOFF)                                   \
    {                                                                          \
        WAITV4;                                                                \
        unsigned aoff = (((unsigned)(KS) * 32u) + (unsigned)g * 8u) ^ swz8;    \
        short8v a0h = *reinterpret_cast<const short8v*>(qh_lds + r * DD + aoff);          \
        short8v a0l = *reinterpret_cast<const short8v*>(ql_lds + r * DD + aoff);          \
        short8v a1h = *reinterpret_cast<const short8v*>(qh_lds + (r + 16) * DD + aoff);   \
        short8v a1l = *reinterpret_cast<const short8v*>(ql_lds + (r + 16) * DD + aoff);   \
        int4v dhwa, dlwa, dhwb, dlwb;                                          \
        CVT2(dhwa, dlwa, 0, CA0.x, CA0.y, ssqa)                                \
        CVT2(dhwa, dlwa, 1, CA0.z, CA0.w, ssqa)                                \
        CVT2(dhwa, dlwa, 2, CA1.x, CA1.y, ssqa)                                \
        CVT2(dhwa, dlwa, 3, CA1.z, CA1.w, ssqa)                                \
        GLOAD(CA0, (const float4*)(prow_a + (PFOFF)));                         \
        GLOAD(CA1, (const float4*)(prow_a + (PFOFF) + 4));                     \
        CVT2(dhwb, dlwb, 0, CB0.x, CB0.y, ssqb)                                \
        CVT2(dhwb, dlwb, 1, CB0.z, CB0.w, ssqb)                                \
        CVT2(dhwb, dlwb, 2, CB1.x, CB1.y, ssqb)                                \
        CVT2(dhwb, dlwb, 3, CB1.z, CB1.w, ssqb)                                \
        GLOAD(CB0, (const float4*)(prow_b + (PFOFF)));                         \
        GLOAD(CB1, (const float4*)(prow_b + (PFOFF) + 4));                     \
        short8v dha = __builtin_bit_cast(short8v, dhwa);                       \
        short8v dla = __builtin_bit_cast(short8v, dlwa);                       \
        c0a = __builtin_amdgcn_mfma_f32_16x16x32_bf16(a0h, dha, c0a, 0, 0, 0); \
        c1a = __builtin_amdgcn_mfma_f32_16x16x32_bf16(a1h, dha, c1a, 0, 0, 0); \
        c0a = __builtin_amdgcn_mfma_f32_16x16x32_bf16(a0h, dla, c0a, 0, 0, 0); \
        c1a = __builtin_amdgcn_mfma_f32_16x16x32_bf16(a1h, dla, c1a, 0, 0, 0); \
        c0a = __builtin_amdgcn_mfma_f32_16x16x32_bf16(a0l, dha, c0a, 0, 0, 0); \
        c1a = __builtin_amdgcn_mfma_f32_16x16x32_bf16(a1l, dha, c1a, 0, 0, 0); \
        short8v dhb = __builtin_bit_cast(short8v, dhwb);                       \
        short8v dlb = __builtin_bit_cast(short8v, dlwb);                       \
        c0b = __builtin_amdgcn_mfma_f32_16x16x32_bf16(a0h, dhb, c0b, 0, 0, 0); \
        c1b = __builtin_amdgcn_mfma_f32_16x16x32_bf16(a1h, dhb, c1b, 0, 0, 0); \
        c0b = __builtin_amdgcn_mfma_f32_16x16x32_bf16(a0h, dlb, c0b, 0, 0, 0); \
        c1b = __builtin_amdgcn_mfma_f32_16x16x32_bf16(a1h, dlb, c1b, 0, 0, 0); \
        c0b = __builtin_amdgcn_mfma_f32_16x16x32_bf16(a0l, dhb, c0b, 0, 0, 0); \
        c1b = __builtin_amdgcn_mfma_f32_16x16x32_bf16(a1l, dhb, c1b, 0, 0, 0); \
    }

    // per-lane row pointers for the two streams (same geometry, two tensors)
    const float* prow_a = d_cq   + (size_t)nb * (LD * DD) + (size_t)(w * 64 + r) * DD + g * 8;
    const float* prow_b = d_orig + (size_t)nb * (LD * DD) + (size_t)(w * 64 + r) * DD + g * 8;

    // prologue fills X=ks0, Y=ks1 (8 loads), then DRAIN so nothing is in
    // flight across the loop pre-header (no phi-copy-of-in-flight-reg hazard)
    float4 Xa0, Xa1, Xb0, Xb1, Ya0, Ya1, Yb0, Yb1;
    GLOAD(Xa0, (const float4*)(prow_a));
    GLOAD(Xa1, (const float4*)(prow_a + 4));
    GLOAD(Xb0, (const float4*)(prow_b));
    GLOAD(Xb1, (const float4*)(prow_b + 4));
    GLOAD(Ya0, (const float4*)(prow_a + 32));
    GLOAD(Ya1, (const float4*)(prow_a + 36));
    GLOAD(Yb0, (const float4*)(prow_b + 32));
    GLOAD(Yb1, (const float4*)(prow_b + 36));
    DRAIN0;

#pragma unroll 1
    for (int nt = 0; nt < 4; ++nt) {
        f32x4 c0a = {0.f, 0.f, 0.f, 0.f}, c1a = {0.f, 0.f, 0.f, 0.f};
        f32x4 c0b = {0.f, 0.f, 0.f, 0.f}, c1b = {0.f, 0.f, 0.f, 0.f};
        float ssqa = 0.0f, ssqb = 0.0f;

        int mk = (nt == 0) ? mk0 : (nt == 1) ? mk1 : (nt == 2) ? mk2 : mk3;
        int nnoff = (nt < 3) ? 2048 : 0;          // next-nt (16 rows) or clamp

        // r12-verified distance-2 schedule: X=ks0,ks2; Y=ks1,ks3
        KSTEP(Xa0, Xa1, Xb0, Xb1, 0, 64);          SB;  // fetch ks2 -> X
        KSTEP(Ya0, Ya1, Yb0, Yb1, 1, 96);          SB;  // fetch ks3 -> Y
        KSTEP(Xa0, Xa1, Xb0, Xb1, 2, nnoff);       SB;  // fetch nt+1 ks0 -> X
        KSTEP(Ya0, Ya1, Yb0, Yb1, 3, nnoff + 32);  SB;  // fetch nt+1 ks1 -> Y

        // drain before back-edge: no asm load in flight across the join
        DRAIN0;

        ssqa += __shfl_xor(ssqa, 16);  ssqa += __shfl_xor(ssqa, 32);
        ssqb += __shfl_xor(ssqb, 16);  ssqb += __shfl_xor(ssqb, 32);
        float inva = 1.0f / fmaxf(sqrtf(ssqa), EPSN);
        float invb = 1.0f / fmaxf(sqrtf(ssqb), EPSN);

        // C layout: col = lane&15 = local d-row; row(lq) = g*4+i (+16 for c1)
#pragma unroll
        for (int i = 0; i < 4; ++i) {
            rm0a[i] = fmaxf(rm0a[i], mk ? c0a[i] * inva : NEGV);
            rm1a[i] = fmaxf(rm1a[i], mk ? c1a[i] * inva : NEGV);
            rm0b[i] = fmaxf(rm0b[i], mk ? c0b[i] * invb : NEGV);
            rm1b[i] = fmaxf(rm1b[i], mk ? c1b[i] * invb : NEGV);
        }
        prow_a += 16 * DD;
        prow_b += 16 * DD;
    }
#undef KSTEP
#undef CVT2
#undef GLOAD
#undef WAITV4
#undef DRAIN0

    // max over the wave's 64 d-rows: reduce across the 16 cols (lane&15)
#pragma unroll
    for (int i = 0; i < 4; ++i) {
#pragma unroll
        for (int o = 1; o <= 8; o <<= 1) {
            rm0a[i] = fmaxf(rm0a[i], __shfl_xor(rm0a[i], o));
            rm1a[i] = fmaxf(rm1a[i], __shfl_xor(rm1a[i], o));
            rm0b[i] = fmaxf(rm0b[i], __shfl_xor(rm0b[i], o));
            rm1b[i] = fmaxf(rm1b[i], __shfl_xor(rm1b[i], o));
        }
    }
    if (r == 0) {
#pragma unroll
        for (int i = 0; i < 4; ++i) {
            wma[w][g * 4 + i]      = rm0a[i];
            wma[w][16 + g * 4 + i] = rm1a[i];
            wmb[w][g * 4 + i]      = rm0b[i];
            wmb[w][16 + g * 4 + i] = rm1b[i];
        }
    }
    __syncthreads();

    if (tid < 64) {   // lanes 0-31: cq, lanes 32-63: orig; l = lq
        int tau = tid >> 5, l = tid & 31;
        const float (*wm)[32] = tau ? wmb : wma;
        float v = fmaxf(fmaxf(wm[0][l], wm[1][l]),
                        fmaxf(wm[2][l], wm[3][l]));
#pragma unroll
        for (int o = 1; o <= 16; o <<= 1) v += __shfl_xor(v, o);
        if (l == 0)
            scores[tau * (Bq * Nn) + b * Nn + n] = v;
    }
}

// ---------------- Kernel 3: log_softmax + KL ----------------
__global__ void loss_k(const float* __restrict__ scores, float* __restrict__ out) {
    int tid = threadIdx.x;   // 128 threads, one per b
    const float* s = scores + tid * Nn;            // student (cq)
    const float* t = scores + Bq * Nn + tid * Nn;  // teacher (orig)
    float sv[Nn], tv[Nn];
#pragma unroll
    for (int n = 0; n < Nn; ++n) { sv[n] = s[n]; tv[n] = t[n]; }
    float ms = sv[0], mt = tv[0];
#pragma unroll
    for (int n = 1; n < Nn; ++n) { ms = fmaxf(ms, sv[n]); mt = fmaxf(mt, tv[n]); }
    float es = 0.0f, et = 0.0f;
#pragma unroll
    for (int n = 0; n < Nn; ++n) { es += expf(sv[n] - ms); et += expf(tv[n] - mt); }
    float lses = ms + logf(es);
    float lset = mt + logf(et);
    double kl = 0.0;
#pragma unroll
    for (int n = 0; n < Nn; ++n) {
        float lt = tv[n] - lset;
        float ls = sv[n] - lses;
        kl += (double)expf(lt) * ((double)lt - (double)ls);
    }
#pragma unroll
    for (int o = 32; o; o >>= 1) kl += __shfl_xor(kl, o);
    __shared__ double part[2];
    if ((tid & 63) == 0) part[tid >> 6] = kl;
    __syncthreads();
    if (tid == 0) out[0] = (float)((part[0] + part[1]) / (double)Bq);
}

extern "C" void kernel_launch(void* const* d_in, const int* in_sizes, int n_in,
                              void* d_out, int out_size, void* d_ws, size_t ws_size,
                              hipStream_t stream) {
    const float* q     = (const float*)d_in[0];
    const float* dcq   = (const float*)d_in[1];
    const float* dorig = (const float*)d_in[2];
    const int*   mask  = (const int*)d_in[3];
    // labels (d_in[4]) unused by the reference loss path

    unsigned short* qh = (unsigned short*)d_ws;                  // [B][32][128] bf16-hi (swizzled rows), 1MB
    unsigned short* ql = qh + (size_t)Bq * LQ * DD;              // bf16-lo (swizzled rows), 1MB
    float* scores      = (float*)(ql + (size_t)Bq * LQ * DD);    // [2][B][N], 8KB

    qnorm_k<<<(Bq * LQ) / 4, 256, 0, stream>>>(q, qh, ql);
    maxsim_k<<<Nn * Bq, 256, 0, stream>>>(dcq, dorig, mask, qh, ql, scores);
    loss_k<<<1, 128, 0, stream>>>(scores, (float*)d_out);
}